// Round 6
// baseline (470.784 us; speedup 1.0000x reference)
//
#include <hip/hip_runtime.h>
#include <hip/hip_bf16.h>
#include <cstdint>
#include <cstddef>

typedef unsigned short u16;
typedef __attribute__((ext_vector_type(8))) __bf16 bf16x8;
typedef __attribute__((ext_vector_type(4))) float floatx4;

#define B_    2
#define S_    2048
#define HID_  2048
#define NH_   16
#define NKV_  4
#define HD_   128
#define QKVN_ 3072   // NH*HD + 2*NKV*HD

__device__ __forceinline__ float bf2f(u16 u) {
  union { unsigned int i; float f; } v; v.i = ((unsigned int)u) << 16; return v.f;
}
__device__ __forceinline__ u16 f2bf(float f) {
  union { float f; unsigned int i; } v; v.f = f;
  unsigned int u = v.i;
  return (u16)((u + 0x7fffu + ((u >> 16) & 1u)) >> 16);  // RNE
}

// async global->LDS, 16B per lane; lane i lands at (wave-uniform base) + i*16.
#define GLOAD_LDS16(gp, lp)                                                  \
  __builtin_amdgcn_global_load_lds(                                          \
      (__attribute__((address_space(1))) void*)(gp),                         \
      (__attribute__((address_space(3))) void*)(lp), 16, 0, 0)

// ---------------------------------------------------------------------------
// f32 -> bf16 (RNE), 8 elements/thread, 16B stores. n % 2048 == 0.
// ---------------------------------------------------------------------------
__global__ __launch_bounds__(256)
void cast_f32_bf16(const float* __restrict__ in, u16* __restrict__ out, int n)
{
  const int i = (blockIdx.x * 256 + threadIdx.x) * 8;
  if (i >= n) return;
  const float4 a = *(const float4*)(in + i);
  const float4 b = *(const float4*)(in + i + 4);
  union { u16 h[8]; uint4 v; } o;
  o.h[0] = f2bf(a.x); o.h[1] = f2bf(a.y); o.h[2] = f2bf(a.z); o.h[3] = f2bf(a.w);
  o.h[4] = f2bf(b.x); o.h[5] = f2bf(b.y); o.h[6] = f2bf(b.z); o.h[7] = f2bf(b.w);
  *(uint4*)(out + i) = o.v;
}

// ---------------------------------------------------------------------------
// C[M,N] = A[M,K] @ W[N,K]^T, bf16 in, fp32 accum. Output bf16 (F32OUT=false)
// or f32 (F32OUT=true — the reference's output dtype for the final GEMM).
// m97 structure; A row stride = lda, C row stride = ldc (W stride = K).
// ---------------------------------------------------------------------------
template <bool F32OUT>
__global__ __launch_bounds__(256, 2)
void gemm_bt_128(const u16* __restrict__ A, const u16* __restrict__ W,
                 void* __restrict__ Cv, int N, int K, int lda, int ldc)
{
  __shared__ __align__(16) u16 lA[128 * 64];
  __shared__ __align__(16) u16 lB[128 * 64];
  const int tid  = threadIdx.x;
  const int w    = tid >> 6, ln = tid & 63;
  const int quad = ln >> 4,  l15 = ln & 15;
  const int m0 = blockIdx.y * 128, n0 = blockIdx.x * 128;
  const int waveM = (w >> 1) * 64, waveN = (w & 1) * 64;

  const floatx4 vzero = {0.f, 0.f, 0.f, 0.f};
  floatx4 acc[4][4];
#pragma unroll
  for (int i = 0; i < 4; ++i)
#pragma unroll
    for (int j = 0; j < 4; ++j) acc[i][j] = vzero;

  for (int k0 = 0; k0 < K; k0 += 64) {
    __syncthreads();   // previous iteration's LDS readers done
#pragma unroll
    for (int p = 0; p < 4; ++p) {
      const int L = (p * 4 + w) * 64 + ln;       // linear 16B-chunk index
      const int row = L >> 3, c = L & 7;         // natural layout
      GLOAD_LDS16(A + (size_t)(m0 + row) * lda + k0 + c * 8, lA + L * 8);
      GLOAD_LDS16(W + (size_t)(n0 + row) * K   + k0 + c * 8, lB + L * 8);
    }
    __syncthreads();   // drains vmcnt for global_load_lds
#pragma unroll
    for (int kk = 0; kk < 64; kk += 32) {
      bf16x8 aF[4], bF[4];
      const int cbase = (kk >> 3) + quad;        // chunk holding k = kk + quad*8
#pragma unroll
      for (int t = 0; t < 4; ++t) {
        const int rowA = waveM + t * 16 + l15;
        aF[t] = *(const bf16x8*)(lA + rowA * 64 + cbase * 8);
        const int rowB = waveN + t * 16 + l15;
        bF[t] = *(const bf16x8*)(lB + rowB * 64 + cbase * 8);
      }
#pragma unroll
      for (int i = 0; i < 4; ++i)
#pragma unroll
        for (int j = 0; j < 4; ++j)
          acc[i][j] = __builtin_amdgcn_mfma_f32_16x16x32_bf16(aF[i], bF[j], acc[i][j], 0, 0, 0);
    }
  }
  // epilogue: C/D layout row = quad*4+reg, col = lane&15 (m89-verified)
#pragma unroll
  for (int i = 0; i < 4; ++i)
#pragma unroll
    for (int r = 0; r < 4; ++r) {
      const int row = m0 + waveM + i * 16 + quad * 4 + r;
      if (F32OUT) {
        float* cp = (float*)Cv + (size_t)row * ldc + n0 + waveN + l15;
#pragma unroll
        for (int j = 0; j < 4; ++j) cp[j * 16] = acc[i][j][r];
      } else {
        u16* cp = (u16*)Cv + (size_t)row * ldc + n0 + waveN + l15;
#pragma unroll
        for (int j = 0; j < 4; ++j) cp[j * 16] = f2bf(acc[i][j][r]);
      }
    }
}

// ---------------------------------------------------------------------------
// RoPE in place on q,k slices of qkv (bf16); copy v out transposed (B,NKV,HD,S).
// position_ids is arange(S) broadcast -> pos = s.
// ---------------------------------------------------------------------------
__global__ __launch_bounds__(256)
void rope_inplace(u16* __restrict__ qkv, u16* __restrict__ vt_ws)
{
  const int s = blockIdx.x, b = blockIdx.y;
  const int tid = threadIdx.x;
  __shared__ float cs[64], sn[64];
  if (tid < 64) {
    const float inv = powf(10000.0f, -((float)tid) / 64.0f);
    float s_, c_;
    sincosf((float)s * inv, &s_, &c_);
    cs[tid] = c_; sn[tid] = s_;
  }
  __syncthreads();
  u16* base = qkv + ((size_t)b * S_ + s) * QKVN_;
  for (int p = tid; p < NH_ * 64; p += 256) {          // q: 16 heads x 64 pairs
    const int h = p >> 6, i = p & 63;
    u16* hp = base + h * 128;
    const float x1 = bf2f(hp[i]);
    const float x2 = bf2f(hp[64 + i]);
    hp[i]      = f2bf(x1 * cs[i] - x2 * sn[i]);
    hp[64 + i] = f2bf(x2 * cs[i] + x1 * sn[i]);
  }
  for (int p = tid; p < NKV_ * 64; p += 256) {         // k: 4 heads x 64 pairs
    const int h = p >> 6, i = p & 63;
    u16* hp = base + NH_ * HD_ + h * 128;
    const float x1 = bf2f(hp[i]);
    const float x2 = bf2f(hp[64 + i]);
    hp[i]      = f2bf(x1 * cs[i] - x2 * sn[i]);
    hp[64 + i] = f2bf(x2 * cs[i] + x1 * sn[i]);
  }
  for (int p = tid; p < NKV_ * HD_; p += 256) {        // v -> v^T (d-major)
    const int h = p >> 7, d = p & 127;
    vt_ws[((size_t)(b * NKV_ + h) * HD_ + d) * S_ + s] =
        base[NH_ * HD_ + NKV_ * HD_ + h * 128 + d];
  }
}

// ---------------------------------------------------------------------------
// Flash attention, causal, GQA. Q,K read from roped qkv (row stride 3072).
// Output written IN PLACE over qkv's Q-columns (block-exclusive rows/cols;
// Q register-resident before writes; K/V columns untouched).
// Block = 64 q rows x head x batch; 4 waves, 16 q rows each; 32-key tiles.
// ---------------------------------------------------------------------------
#define LKP  136   // 128 + 8
#define LVP  40    // 32 + 8
__global__ __launch_bounds__(256, 2)
void flash_attn(u16* __restrict__ qkv, const u16* __restrict__ vt_ws)
{
  const int qb = blockIdx.x;
  const int h  = blockIdx.y;
  const int b  = blockIdx.z;
  const int tid  = threadIdx.x;
  const int w    = tid >> 6, ln = tid & 63;
  const int quad = ln >> 4,  l15 = ln & 15;
  const int kvh  = h >> 2;
  const int qrow0 = qb * 64 + w * 16;

  __shared__ __align__(16) u16 lK[32 * LKP];     // [key][d]
  __shared__ __align__(16) u16 lVt[128 * LVP];   // [d][key]
  __shared__ __align__(16) u16 lP[4][16 * LVP];  // per-wave P staging

  // Q fragments: A[m=lane&15][k=quad*8+j], 4 chunks of K=32
  bf16x8 qF[4];
  {
    const u16* qp = qkv + ((size_t)(b * S_) + qrow0 + l15) * QKVN_ + h * HD_;
#pragma unroll
    for (int c = 0; c < 4; ++c)
      qF[c] = *(const bf16x8*)(qp + c * 32 + quad * 8);
  }

  const floatx4 vzero = {0.f, 0.f, 0.f, 0.f};
  float m_i[4], l_i[4];
  floatx4 Oacc[8];
#pragma unroll
  for (int r = 0; r < 4; ++r) { m_i[r] = -1e30f; l_i[r] = 0.f; }
#pragma unroll
  for (int t = 0; t < 8; ++t) Oacc[t] = vzero;

  const float scale = 0.08838834764831845f;  // 1/sqrt(128)
  const u16* kbase = qkv + (size_t)b * S_ * QKVN_ + NH_ * HD_ + kvh * HD_;
  const u16* vbase = vt_ws + (size_t)(b * NKV_ + kvh) * HD_ * S_;
  const int ktEnd = qb * 2 + 2;

  for (int kt = 0; kt < ktEnd; ++kt) {
    __syncthreads();   // previous iteration's LDS readers done
#pragma unroll
    for (int p = 0; p < 2; ++p) {
      const int u = tid + p * 256;
      const int key = u >> 4, cslot = u & 15;
      *(uint4*)(lK + key * LKP + cslot * 8) =
          *(const uint4*)(kbase + (size_t)(kt * 32 + key) * QKVN_ + cslot * 8);
      const int d = u >> 2, c2 = u & 3;
      *(uint4*)(lVt + d * LVP + c2 * 8) =
          *(const uint4*)(vbase + (size_t)d * S_ + kt * 32 + c2 * 8);
    }
    __syncthreads();

    // S = Q K^T : two 16-key column tiles
    floatx4 sc[2];
#pragma unroll
    for (int nt = 0; nt < 2; ++nt) {
      floatx4 a = vzero;
      const int keyloc = nt * 16 + l15;
#pragma unroll
      for (int c = 0; c < 4; ++c) {
        const bf16x8 kF = *(const bf16x8*)(lK + keyloc * LKP + (c * 4 + quad) * 8);
        a = __builtin_amdgcn_mfma_f32_16x16x32_bf16(qF[c], kF, a, 0, 0, 0);
      }
      sc[nt] = a;
    }

    // online softmax (q row = quad*4+r; 16 keys spread over l15 lanes)
    float pr[2][4];
#pragma unroll
    for (int r = 0; r < 4; ++r) {
      const int qrow = qrow0 + quad * 4 + r;
      const int key0 = kt * 32 + l15;
      float s0 = sc[0][r] * scale + ((key0      <= qrow) ? 0.f : -1e9f);
      float s1 = sc[1][r] * scale + ((key0 + 16 <= qrow) ? 0.f : -1e9f);
      float mx = fmaxf(s0, s1);
#pragma unroll
      for (int off = 1; off < 16; off <<= 1) mx = fmaxf(mx, __shfl_xor(mx, off, 64));
      const float mn = fmaxf(m_i[r], mx);
      const float alpha = __expf(m_i[r] - mn);
      const float p0 = __expf(s0 - mn);
      const float p1 = __expf(s1 - mn);
      float sm = p0 + p1;
#pragma unroll
      for (int off = 1; off < 16; off <<= 1) sm += __shfl_xor(sm, off, 64);
      l_i[r] = l_i[r] * alpha + sm;
      m_i[r] = mn;
      pr[0][r] = p0; pr[1][r] = p1;
#pragma unroll
      for (int t = 0; t < 8; ++t) Oacc[t][r] *= alpha;
    }

    // P (16x32) -> per-wave LDS staging (A-operand layout, padded rows)
#pragma unroll
    for (int nt = 0; nt < 2; ++nt)
#pragma unroll
      for (int r = 0; r < 4; ++r)
        lP[w][(quad * 4 + r) * LVP + nt * 16 + l15] = f2bf(pr[nt][r]);
    __syncthreads();   // uniform; covers the wave-local P write->read

    // O += P V : A = P[m=qrow][k=key], B = V^T[n=d][k=key]
    {
      const bf16x8 pF = *(const bf16x8*)(&lP[w][l15 * LVP + quad * 8]);
#pragma unroll
      for (int t = 0; t < 8; ++t) {
        const int d = t * 16 + l15;
        const bf16x8 vF = *(const bf16x8*)(lVt + d * LVP + quad * 8);
        Oacc[t] = __builtin_amdgcn_mfma_f32_16x16x32_bf16(pF, vF, Oacc[t], 0, 0, 0);
      }
    }
  }

  // epilogue: normalize, write over qkv Q-slice: row stride QKVN_, col h*128+d
#pragma unroll
  for (int r = 0; r < 4; ++r) l_i[r] = 1.0f / l_i[r];
#pragma unroll
  for (int t = 0; t < 8; ++t) {
    const int d = t * 16 + l15;
#pragma unroll
    for (int r = 0; r < 4; ++r) {
      const int qrow = qrow0 + quad * 4 + r;
      qkv[((size_t)(b * S_ + qrow)) * QKVN_ + h * HD_ + d] = f2bf(Oacc[t][r] * l_i[r]);
    }
  }
}

// ---------------------------------------------------------------------------
// d_out is FLOAT32 (reference output dtype). During the pipeline its first
// 16.8 MB serve as bf16 scratch (xb, then vt); gemm2 overwrites all of d_out
// with the final f32 result last.
// ws: [qkv 12.58M u16][slotW 6.29M u16] = 37.75 MB.
// ---------------------------------------------------------------------------
extern "C" void kernel_launch(void* const* d_in, const int* in_sizes, int n_in,
                              void* d_out, int out_size, void* d_ws, size_t ws_size,
                              hipStream_t stream)
{
  (void)in_sizes; (void)n_in; (void)out_size; (void)ws_size;
  const float* x     = (const float*)d_in[0];   // f32 per reference dtypes
  // d_in[1] = position_ids (arange) — analytic; d_in[2] = causal mask — analytic
  const float* w_qkv = (const float*)d_in[3];
  const float* w_o   = (const float*)d_in[4];
  float* out = (float*)d_out;                   // f32 output!

  const int nX  = B_ * S_ * HID_;               // 8.39M
  const int nWq = QKVN_ * HID_;                 // 6.29M
  const int nWo = HID_ * HID_;                  // 4.19M

  u16* ws    = (u16*)d_ws;
  u16* qkv   = ws;                              // 12.58M u16
  u16* slotW = qkv + (size_t)(B_ * S_) * QKVN_; // 6.29M u16
  u16* xb    = (u16*)d_out;                     // bf16 scratch inside f32 d_out
  u16* vt_ws = (u16*)d_out;                     // reused after gemm1 (2.10M u16)

  const dim3 blk(256);
  // 0) casts (f32 -> bf16): x -> d_out scratch, w_qkv -> slotW
  cast_f32_bf16<<<nX  / 2048, blk, 0, stream>>>(x,     xb,    nX);
  cast_f32_bf16<<<nWq / 2048, blk, 0, stream>>>(w_qkv, slotW, nWq);
  // 1) qkv = x @ w_qkv^T   (M=4096, N=3072, K=2048), bf16 out
  gemm_bt_128<false><<<dim3(QKVN_ / 128, (B_ * S_) / 128), blk, 0, stream>>>(
      xb, slotW, qkv, QKVN_, HID_, HID_, QKVN_);
  // 2) RoPE in place + V^T -> d_out scratch (xb dead)
  rope_inplace<<<dim3(S_, B_), blk, 0, stream>>>(qkv, vt_ws);
  // 2b) cast w_o into slotW (wqb dead after gemm1)
  cast_f32_bf16<<<nWo / 2048, blk, 0, stream>>>(w_o, slotW, nWo);
  // 3) causal GQA flash attention, writes attn into qkv Q-columns
  flash_attn<<<dim3(S_ / 64, NH_, B_), blk, 0, stream>>>(qkv, vt_ws);
  // 4) out = attn @ w_o^T  (M=4096, N=2048, K=2048), f32 out, attn lda=3072
  gemm_bt_128<true><<<dim3(HID_ / 128, (B_ * S_) / 128), blk, 0, stream>>>(
      qkv, slotW, out, HID_, HID_, QKVN_, HID_);
}

// Round 7
// 404.312 us; speedup vs baseline: 1.1644x; 1.1644x over previous
//
#include <hip/hip_runtime.h>
#include <hip/hip_bf16.h>
#include <cstdint>
#include <cstddef>

typedef unsigned short u16;
typedef __attribute__((ext_vector_type(8))) __bf16 bf16x8;
typedef __attribute__((ext_vector_type(4))) float floatx4;

#define B_    2
#define S_    2048
#define HID_  2048
#define NH_   16
#define NKV_  4
#define HD_   128
#define QKVN_ 3072   // NH*HD + 2*NKV*HD

__device__ __forceinline__ float bf2f(u16 u) {
  union { unsigned int i; float f; } v; v.i = ((unsigned int)u) << 16; return v.f;
}
__device__ __forceinline__ u16 f2bf(float f) {
  union { float f; unsigned int i; } v; v.f = f;
  unsigned int u = v.i;
  return (u16)((u + 0x7fffu + ((u >> 16) & 1u)) >> 16);  // RNE
}

// async global->LDS, 16B per lane; lane i lands at (wave-uniform base) + i*16.
#define GLOAD_LDS16(gp, lp)                                                  \
  __builtin_amdgcn_global_load_lds(                                          \
      (__attribute__((address_space(1))) void*)(gp),                         \
      (__attribute__((address_space(3))) void*)(lp), 16, 0, 0)

// ---------------------------------------------------------------------------
// f32 -> bf16 (RNE), 8 elements/thread, 16B stores. n % 2048 == 0.
// ---------------------------------------------------------------------------
__global__ __launch_bounds__(256)
void cast_f32_bf16(const float* __restrict__ in, u16* __restrict__ out, int n)
{
  const int i = (blockIdx.x * 256 + threadIdx.x) * 8;
  if (i >= n) return;
  const float4 a = *(const float4*)(in + i);
  const float4 b = *(const float4*)(in + i + 4);
  union { u16 h[8]; uint4 v; } o;
  o.h[0] = f2bf(a.x); o.h[1] = f2bf(a.y); o.h[2] = f2bf(a.z); o.h[3] = f2bf(a.w);
  o.h[4] = f2bf(b.x); o.h[5] = f2bf(b.y); o.h[6] = f2bf(b.z); o.h[7] = f2bf(b.w);
  *(uint4*)(out + i) = o.v;
}

// ---------------------------------------------------------------------------
// C[M,N] = A[M,K] @ W[N,K]^T, bf16 in, fp32 accum. Output bf16 (F32OUT=false)
// or f32 (F32OUT=true). m97 structure; A row stride lda, C row stride ldc.
// ---------------------------------------------------------------------------
template <bool F32OUT>
__global__ __launch_bounds__(256, 2)
void gemm_bt_128(const u16* __restrict__ A, const u16* __restrict__ W,
                 void* __restrict__ Cv, int N, int K, int lda, int ldc)
{
  __shared__ __align__(16) u16 lA[128 * 64];
  __shared__ __align__(16) u16 lB[128 * 64];
  const int tid  = threadIdx.x;
  const int w    = tid >> 6, ln = tid & 63;
  const int quad = ln >> 4,  l15 = ln & 15;
  const int m0 = blockIdx.y * 128, n0 = blockIdx.x * 128;
  const int waveM = (w >> 1) * 64, waveN = (w & 1) * 64;

  const floatx4 vzero = {0.f, 0.f, 0.f, 0.f};
  floatx4 acc[4][4];
#pragma unroll
  for (int i = 0; i < 4; ++i)
#pragma unroll
    for (int j = 0; j < 4; ++j) acc[i][j] = vzero;

  for (int k0 = 0; k0 < K; k0 += 64) {
    __syncthreads();   // previous iteration's LDS readers done
#pragma unroll
    for (int p = 0; p < 4; ++p) {
      const int L = (p * 4 + w) * 64 + ln;       // linear 16B-chunk index
      const int row = L >> 3, c = L & 7;         // natural layout
      GLOAD_LDS16(A + (size_t)(m0 + row) * lda + k0 + c * 8, lA + L * 8);
      GLOAD_LDS16(W + (size_t)(n0 + row) * K   + k0 + c * 8, lB + L * 8);
    }
    __syncthreads();   // drains vmcnt for global_load_lds
#pragma unroll
    for (int kk = 0; kk < 64; kk += 32) {
      bf16x8 aF[4], bF[4];
      const int cbase = (kk >> 3) + quad;        // chunk holding k = kk + quad*8
#pragma unroll
      for (int t = 0; t < 4; ++t) {
        const int rowA = waveM + t * 16 + l15;
        aF[t] = *(const bf16x8*)(lA + rowA * 64 + cbase * 8);
        const int rowB = waveN + t * 16 + l15;
        bF[t] = *(const bf16x8*)(lB + rowB * 64 + cbase * 8);
      }
#pragma unroll
      for (int i = 0; i < 4; ++i)
#pragma unroll
        for (int j = 0; j < 4; ++j)
          acc[i][j] = __builtin_amdgcn_mfma_f32_16x16x32_bf16(aF[i], bF[j], acc[i][j], 0, 0, 0);
    }
  }
  // epilogue: C/D layout row = quad*4+reg, col = lane&15 (m89-verified)
#pragma unroll
  for (int i = 0; i < 4; ++i)
#pragma unroll
    for (int r = 0; r < 4; ++r) {
      const int row = m0 + waveM + i * 16 + quad * 4 + r;
      if (F32OUT) {
        float* cp = (float*)Cv + (size_t)row * ldc + n0 + waveN + l15;
#pragma unroll
        for (int j = 0; j < 4; ++j) cp[j * 16] = acc[i][j][r];
      } else {
        u16* cp = (u16*)Cv + (size_t)row * ldc + n0 + waveN + l15;
#pragma unroll
        for (int j = 0; j < 4; ++j) cp[j * 16] = f2bf(acc[i][j][r]);
      }
    }
}

// ---------------------------------------------------------------------------
// RoPE in place on q,k slices of qkv (bf16); copy v out transposed (B,NKV,HD,S).
// ---------------------------------------------------------------------------
__global__ __launch_bounds__(256)
void rope_inplace(u16* __restrict__ qkv, u16* __restrict__ vt_ws)
{
  const int s = blockIdx.x, b = blockIdx.y;
  const int tid = threadIdx.x;
  __shared__ float cs[64], sn[64];
  if (tid < 64) {
    const float inv = powf(10000.0f, -((float)tid) / 64.0f);
    float s_, c_;
    sincosf((float)s * inv, &s_, &c_);
    cs[tid] = c_; sn[tid] = s_;
  }
  __syncthreads();
  u16* base = qkv + ((size_t)b * S_ + s) * QKVN_;
  for (int p = tid; p < NH_ * 64; p += 256) {          // q: 16 heads x 64 pairs
    const int h = p >> 6, i = p & 63;
    u16* hp = base + h * 128;
    const float x1 = bf2f(hp[i]);
    const float x2 = bf2f(hp[64 + i]);
    hp[i]      = f2bf(x1 * cs[i] - x2 * sn[i]);
    hp[64 + i] = f2bf(x2 * cs[i] + x1 * sn[i]);
  }
  for (int p = tid; p < NKV_ * 64; p += 256) {         // k: 4 heads x 64 pairs
    const int h = p >> 6, i = p & 63;
    u16* hp = base + NH_ * HD_ + h * 128;
    const float x1 = bf2f(hp[i]);
    const float x2 = bf2f(hp[64 + i]);
    hp[i]      = f2bf(x1 * cs[i] - x2 * sn[i]);
    hp[64 + i] = f2bf(x2 * cs[i] + x1 * sn[i]);
  }
  for (int p = tid; p < NKV_ * HD_; p += 256) {        // v -> v^T (d-major)
    const int h = p >> 7, d = p & 127;
    vt_ws[((size_t)(b * NKV_ + h) * HD_ + d) * S_ + s] =
        base[NH_ * HD_ + NKV_ * HD_ + h * 128 + d];
  }
}

// ---------------------------------------------------------------------------
// Flash attention, causal, GQA. 64-KEY tiles + balanced q-tile pairing:
// block pi handles q-tiles {pi, 31-pi} -> every block does exactly 34
// 64-key iterations (uniform load, no tail). Output in place over qkv's
// Q-columns. 4 waves, 16 q rows each per tile.
// ---------------------------------------------------------------------------
#define LKP  136   // 128 + 8
#define LVP  72    // 64 + 8
__global__ __launch_bounds__(256, 2)
void flash_attn(u16* __restrict__ qkv, const u16* __restrict__ vt_ws)
{
  const int pi = blockIdx.x;   // 0..15 (pair index)
  const int h  = blockIdx.y;
  const int b  = blockIdx.z;
  const int tid  = threadIdx.x;
  const int w    = tid >> 6, ln = tid & 63;
  const int quad = ln >> 4,  l15 = ln & 15;
  const int kvh  = h >> 2;

  __shared__ __align__(16) u16 lK[64 * LKP];     // [key][d]
  __shared__ __align__(16) u16 lVt[128 * LVP];   // [d][key]
  __shared__ __align__(16) u16 lP[4][16 * LVP];  // per-wave P staging

  const float scale = 0.08838834764831845f;  // 1/sqrt(128)
  const u16* kbase = qkv + (size_t)b * S_ * QKVN_ + NH_ * HD_ + kvh * HD_;
  const u16* vbase = vt_ws + (size_t)(b * NKV_ + kvh) * HD_ * S_;
  const floatx4 vzero = {0.f, 0.f, 0.f, 0.f};

#pragma unroll 1
  for (int half = 0; half < 2; ++half) {
    const int qt = half ? (31 - pi) : pi;      // paired tiles: equal total work
    const int qrow0 = qt * 64 + w * 16;

    // Q fragments: A[m=lane&15][k=quad*8+j], 4 chunks of K=32
    bf16x8 qF[4];
    {
      const u16* qp = qkv + ((size_t)(b * S_) + qrow0 + l15) * QKVN_ + h * HD_;
#pragma unroll
      for (int c = 0; c < 4; ++c)
        qF[c] = *(const bf16x8*)(qp + c * 32 + quad * 8);
    }

    float m_i[4], l_i[4];
    floatx4 Oacc[8];
#pragma unroll
    for (int r = 0; r < 4; ++r) { m_i[r] = -1e30f; l_i[r] = 0.f; }
#pragma unroll
    for (int t = 0; t < 8; ++t) Oacc[t] = vzero;

    const int ktEnd = qt + 1;                  // 64-key tiles
#pragma unroll 1
    for (int kt = 0; kt < ktEnd; ++kt) {
      __syncthreads();   // previous iteration's LDS readers done
#pragma unroll
      for (int p = 0; p < 4; ++p) {
        const int idx = p * 256 + tid;         // 0..1023 16B-chunks
        const int key = idx >> 4, cslot = idx & 15;
        *(uint4*)(lK + key * LKP + cslot * 8) =
            *(const uint4*)(kbase + (size_t)(kt * 64 + key) * QKVN_ + cslot * 8);
        const int d = idx >> 3, c2 = idx & 7;
        *(uint4*)(lVt + d * LVP + c2 * 8) =
            *(const uint4*)(vbase + (size_t)d * S_ + kt * 64 + c2 * 8);
      }
      __syncthreads();

      // S = Q K^T : four 16-key column tiles
      floatx4 sc[4];
#pragma unroll
      for (int nt = 0; nt < 4; ++nt) {
        floatx4 a = vzero;
        const int keyloc = nt * 16 + l15;
#pragma unroll
        for (int c = 0; c < 4; ++c) {
          const bf16x8 kF = *(const bf16x8*)(lK + keyloc * LKP + (c * 4 + quad) * 8);
          a = __builtin_amdgcn_mfma_f32_16x16x32_bf16(qF[c], kF, a, 0, 0, 0);
        }
        sc[nt] = a;
      }

      // online softmax (q row = quad*4+r; 16 lanes hold 4x16 keys)
      float pr[4][4];
#pragma unroll
      for (int r = 0; r < 4; ++r) {
        const int qrow = qrow0 + quad * 4 + r;
        float s[4];
#pragma unroll
        for (int nt = 0; nt < 4; ++nt) {
          const int key0 = kt * 64 + nt * 16 + l15;
          s[nt] = sc[nt][r] * scale + ((key0 <= qrow) ? 0.f : -1e9f);
        }
        float mx = fmaxf(fmaxf(s[0], s[1]), fmaxf(s[2], s[3]));
#pragma unroll
        for (int off = 1; off < 16; off <<= 1) mx = fmaxf(mx, __shfl_xor(mx, off, 64));
        const float mn = fmaxf(m_i[r], mx);
        const float alpha = __expf(m_i[r] - mn);
        float sm = 0.f;
#pragma unroll
        for (int nt = 0; nt < 4; ++nt) {
          const float p = __expf(s[nt] - mn);
          pr[nt][r] = p;
          sm += p;
        }
#pragma unroll
        for (int off = 1; off < 16; off <<= 1) sm += __shfl_xor(sm, off, 64);
        l_i[r] = l_i[r] * alpha + sm;
        m_i[r] = mn;
#pragma unroll
        for (int t = 0; t < 8; ++t) Oacc[t][r] *= alpha;
      }

      // P (16x64) -> per-wave LDS staging (A-operand layout, padded rows)
#pragma unroll
      for (int nt = 0; nt < 4; ++nt)
#pragma unroll
        for (int r = 0; r < 4; ++r)
          lP[w][(quad * 4 + r) * LVP + nt * 16 + l15] = f2bf(pr[nt][r]);
      __syncthreads();   // covers wave-local P write->read

      // O += P V : A = P[m=qrow][k=key], B = V^T[n=d][k=key]; 2 k-chunks of 32
      {
        const bf16x8 pF0 = *(const bf16x8*)(&lP[w][l15 * LVP + quad * 8]);
        const bf16x8 pF1 = *(const bf16x8*)(&lP[w][l15 * LVP + 32 + quad * 8]);
#pragma unroll
        for (int t = 0; t < 8; ++t) {
          const int d = t * 16 + l15;
          const bf16x8 vF0 = *(const bf16x8*)(lVt + d * LVP + quad * 8);
          const bf16x8 vF1 = *(const bf16x8*)(lVt + d * LVP + 32 + quad * 8);
          Oacc[t] = __builtin_amdgcn_mfma_f32_16x16x32_bf16(pF0, vF0, Oacc[t], 0, 0, 0);
          Oacc[t] = __builtin_amdgcn_mfma_f32_16x16x32_bf16(pF1, vF1, Oacc[t], 0, 0, 0);
        }
      }
    }

    // epilogue: normalize, write over qkv Q-slice (row stride QKVN_)
#pragma unroll
    for (int r = 0; r < 4; ++r) l_i[r] = 1.0f / l_i[r];
#pragma unroll
    for (int t = 0; t < 8; ++t) {
      const int d = t * 16 + l15;
#pragma unroll
      for (int r = 0; r < 4; ++r) {
        const int qrow = qrow0 + quad * 4 + r;
        qkv[((size_t)(b * S_ + qrow)) * QKVN_ + h * HD_ + d] = f2bf(Oacc[t][r] * l_i[r]);
      }
    }
  }
}

// ---------------------------------------------------------------------------
// d_out is FLOAT32 (reference output dtype). Its first 16.8 MB serve as bf16
// scratch (xb, then vt); gemm2 overwrites all of d_out last.
// ws: [qkv 12.58M u16][slotW 6.29M u16] = 37.75 MB.
// ---------------------------------------------------------------------------
extern "C" void kernel_launch(void* const* d_in, const int* in_sizes, int n_in,
                              void* d_out, int out_size, void* d_ws, size_t ws_size,
                              hipStream_t stream)
{
  (void)in_sizes; (void)n_in; (void)out_size; (void)ws_size;
  const float* x     = (const float*)d_in[0];   // f32 per reference dtypes
  // d_in[1] = position_ids (arange) — analytic; d_in[2] = causal mask — analytic
  const float* w_qkv = (const float*)d_in[3];
  const float* w_o   = (const float*)d_in[4];
  float* out = (float*)d_out;                   // f32 output

  const int nX  = B_ * S_ * HID_;               // 8.39M
  const int nWq = QKVN_ * HID_;                 // 6.29M
  const int nWo = HID_ * HID_;                  // 4.19M

  u16* ws    = (u16*)d_ws;
  u16* qkv   = ws;                              // 12.58M u16
  u16* slotW = qkv + (size_t)(B_ * S_) * QKVN_; // 6.29M u16
  u16* xb    = (u16*)d_out;                     // bf16 scratch inside f32 d_out
  u16* vt_ws = (u16*)d_out;                     // reused after gemm1 (2.10M u16)

  const dim3 blk(256);
  // 0) casts (f32 -> bf16): x -> d_out scratch, w_qkv -> slotW
  cast_f32_bf16<<<nX  / 2048, blk, 0, stream>>>(x,     xb,    nX);
  cast_f32_bf16<<<nWq / 2048, blk, 0, stream>>>(w_qkv, slotW, nWq);
  // 1) qkv = x @ w_qkv^T   (M=4096, N=3072, K=2048), bf16 out
  gemm_bt_128<false><<<dim3(QKVN_ / 128, (B_ * S_) / 128), blk, 0, stream>>>(
      xb, slotW, qkv, QKVN_, HID_, HID_, QKVN_);
  // 2) RoPE in place + V^T -> d_out scratch (xb dead)
  rope_inplace<<<dim3(S_, B_), blk, 0, stream>>>(qkv, vt_ws);
  // 2b) cast w_o into slotW (wqb dead after gemm1)
  cast_f32_bf16<<<nWo / 2048, blk, 0, stream>>>(w_o, slotW, nWo);
  // 3) causal GQA flash attention (paired q-tiles), in-place into qkv Q-cols
  flash_attn<<<dim3(16, NH_, B_), blk, 0, stream>>>(qkv, vt_ws);
  // 4) out = attn @ w_o^T  (M=4096, N=2048, K=2048), f32 out, attn lda=3072
  gemm_bt_128<true><<<dim3(HID_ / 128, (B_ * S_) / 128), blk, 0, stream>>>(
      qkv, slotW, out, HID_, HID_, QKVN_, HID_);
}